// Round 5
// baseline (442.388 us; speedup 1.0000x reference)
//
#include <hip/hip_runtime.h>
#include <math.h>

// 8 threads per ray (t = tid&7 owns coarse points/samples/fine points [8t,8t+8)).
// R4 post-mortem: thread-per-ray = 2048 waves = 2/SIMD grid cap -> latency-bound.
// R3 post-mortem: full 64-lane shuffle machinery = 3x issue cost.
// Middle ground: serial within 8-point segments, width-8 shuffle scans (3 steps),
// per-ray LDS arrays (stride RPB+1=33 -> 2-way bank aliasing = free).
// Phase 2 (sampling) needs ZERO sigmoid evals: cdf built from phase-1 weights;
// 9 fixed-trip binary searches per thread. Phase 3 = merge-rank decomposition
// (validated end-to-end in R3): w2A_p = opA*PAexc_p*PB(jB_p), w2B_k = opB*PBexc_k*PA(jA_k),
// jA closed-form vs linspace grid (exact-compare fixup), jB = 6-probe search on fdep.

#define PTS 64
#define NRAYS (2*256*256)
#define NEARV 0.1f
#define STEPV (1.9f/63.0f)
#define INVSTEP (1.0f/(1.9f/63.0f))
#define NL2E (-1.4426950408889634f)
#define RPB 32            // rays per block (256 threads / 8 tpr)

extern "C" __device__ float __ocml_native_exp2_f32(float);

__device__ __forceinline__ float sig_pm(float arg) {   // arg is already -x*log2e
    return __builtin_amdgcn_rcpf(1.0f + __ocml_native_exp2_f32(arg));
}

__global__ __launch_bounds__(256, 5) void nerf_main(
    const float* __restrict__ tm, const float* __restrict__ wq,
    float* __restrict__ out, unsigned int* __restrict__ mmx)
{
    __shared__ float cpb[64][RPB + 1];   // cdf; reused as PB-inclusive after sync
    __shared__ float pai[64][RPB + 1];   // PA-inclusive (coarse prefix products)
    __shared__ float fde[64][RPB + 1];   // fine depths (sorted)

    const int tid = threadIdx.x;
    const int t  = tid & 7;              // segment slot within ray
    const int rl = tid >> 3;             // ray within block
    const int r  = blockIdx.x * RPB + rl;
    const int b  = r >> 16;
    const int n  = r & 65535;
    const int ii = n >> 8;
    const int jj = n & 255;

    const float cx = (1.0f + (float)jj * (-2.0f/255.0f)) * (1.0f/4.2f);
    const float cy = (1.0f + (float)ii * (-2.0f/255.0f)) * (1.0f/4.2f);

    const float* tmb = tm + b*12;
    const float dx = tmb[0]*cx + tmb[1]*cy + tmb[2];
    const float dy = tmb[4]*cx + tmb[5]*cy + tmb[6];
    const float dz = tmb[8]*cx + tmb[9]*cy + tmb[10];
    const float ox = tmb[3], oy = tmb[7], oz = tmb[11];

    float bA[4], sA[4];                  // feat[c]*(-log2e) = bA[c] + d*sA[c]
    #pragma unroll
    for (int c = 0; c < 4; c++) {
        float s  = dx*wq[0*4+c] + dy*wq[1*4+c] + dz*wq[2*4+c];
        float bb = ox*wq[0*4+c] + oy*wq[1*4+c] + oz*wq[2*4+c]
                 + dx*wq[3*4+c] + dy*wq[4*4+c] + dz*wq[5*4+c];
        sA[c] = s * NL2E;
        bA[c] = bb * NL2E;
    }

    // ================= phase 1: coarse segment [8t, 8t+8) =================
    float Tloc[9]; Tloc[0] = 1.0f;
    float pw[8];
    float sv0 = 0.0f, sv1 = 0.0f, sv2 = 0.0f;
    #pragma unroll
    for (int i = 0; i < 8; i++) {
        float d  = fmaf((float)(8*t + i), STEPV, NEARV);
        float op = sig_pm(bA[0] + d*sA[0]);
        float v0 = sig_pm(bA[1] + d*sA[1]);
        float v1 = sig_pm(bA[2] + d*sA[2]);
        float v2 = sig_pm(bA[3] + d*sA[3]);
        pw[i] = op * Tloc[i];
        sv0 = fmaf(pw[i], v0, sv0);
        sv1 = fmaf(pw[i], v1, sv1);
        sv2 = fmaf(pw[i], v2, sv2);
        Tloc[i+1] = Tloc[i] * (1.0f - op);
    }
    // exclusive scan (mul) of segment transmittance over the 8 slots
    float incA = Tloc[8];
    #pragma unroll
    for (int d = 1; d < 8; d <<= 1) { float o = __shfl_up(incA, d, 64); if (t >= d) incA *= o; }
    float exA; { float s = __shfl_up(incA, 1, 64); exA = (t == 0) ? 1.0f : s; }

    float pwsum = pw[0]+pw[1]+pw[2]+pw[3]+pw[4]+pw[5]+pw[6]+pw[7];
    float segwt = fmaf(exA, pwsum, 8e-5f);               // Σ (w + 1e-5) in segment
    float S = segwt;
    #pragma unroll
    for (int m = 1; m < 8; m <<= 1) S += __shfl_xor(S, m, 64);
    const float Sinv = __builtin_amdgcn_rcpf(S);

    float incw = segwt;
    #pragma unroll
    for (int d = 1; d < 8; d <<= 1) { float o = __shfl_up(incw, d, 64); if (t >= d) incw += o; }
    float cb; { float s = __shfl_up(incw, 1, 64); cb = (t == 0) ? 0.0f : s; }

    float a0 = exA*sv0, a1 = exA*sv1, a2 = exA*sv2;
    #pragma unroll
    for (int m = 1; m < 8; m <<= 1) {
        a0 += __shfl_xor(a0, m, 64);
        a1 += __shfl_xor(a1, m, 64);
        a2 += __shfl_xor(a2, m, 64);
    }

    float run = cb;
    #pragma unroll
    for (int i = 0; i < 8; i++) {
        run += fmaf(exA, pw[i], 1e-5f);
        cpb[8*t + i][rl] = run * Sinv;                   // cdf
        pai[8*t + i][rl] = exA * Tloc[i+1];              // PA inclusive
    }
    if (t == 0) {
        out[(b*3+0)*65536 + n] = a0;
        out[(b*3+1)*65536 + n] = a1;
        out[(b*3+2)*65536 + n] = a2;
    }
    __syncthreads();

    // ================= phase 2: bins for u = (8t+m)/64, m=0..8 =================
    const float c63 = cpb[63][rl];
    float fdr[8];
    float bin_prev = 0.0f;
    #pragma unroll
    for (int m = 0; m < 9; m++) {
        float u = (float)(8*t + m) * 0.015625f;          // exact k/64
        int lo = 0;
        #pragma unroll
        for (int s = 32; s >= 1; s >>= 1) {              // probes idx <= 62
            float c = cpb[lo + s - 1][rl];
            if (c <= u) lo += s;                         // searchsorted 'right'
        }
        int ind = (c63 <= u) ? 64 : lo;
        int below = min(max(ind - 1, 0), 63);
        int above = min(ind, 63);
        float c0 = cpb[below][rl];
        float c1 = cpb[above][rl];
        float d0 = fmaf((float)below, STEPV, NEARV);
        float d1 = fmaf((float)above, STEPV, NEARV);
        float den = c1 - c0;
        den = (den < 1e-8f) ? 1.0f : den;                // ref guard (fires at ind==0/equal)
        float tt = (u - c0) * __builtin_amdgcn_rcpf(den);
        tt = fminf(fmaxf(tt, 0.0f), 1.0f);
        float bin = fmaf(tt, d1 - d0, d0);
        if (m > 0) {
            fdr[m-1] = 0.5f * (bin_prev + bin);          // fine depth 8t+m-1
            fde[8*t + m - 1][rl] = fdr[m-1];
        }
        bin_prev = bin;
    }
    __syncthreads();                                     // all cdf reads done -> cpb reusable

    // ================= phase 3a: fine-side (own 8 fine points) =================
    float TB[9]; TB[0] = 1.0f;
    float s0 = 0.0f, s1 = 0.0f, s2 = 0.0f, swf = 0.0f, sdf = 0.0f;
    #pragma unroll
    for (int i = 0; i < 8; i++) {
        float dB  = fdr[i];
        float opB = sig_pm(bA[0] + dB*sA[0]);
        float v0B = sig_pm(bA[1] + dB*sA[1]);
        float v1B = sig_pm(bA[2] + dB*sA[2]);
        float v2B = sig_pm(bA[3] + dB*sA[3]);
        // jA = #{p: d_p <= dB} : closed-form + exact-compare fixup (same fmaf grid as coarse)
        int q0 = (int)floorf((dB - NEARV) * INVSTEP);
        float g0 = fmaf((float)q0,     STEPV, NEARV);
        float g1 = fmaf((float)(q0+1), STEPV, NEARV);
        int jA = q0 + ((g0 <= dB) ? 1 : 0) + ((g1 <= dB) ? 1 : 0);   // in [0,64]
        float PAg = (jA == 0) ? 1.0f : pai[min(jA - 1, 63)][rl];
        float h = opB * TB[i] * PAg;                     // missing exB factor (uniform/thread)
        s0 = fmaf(h, v0B, s0);
        s1 = fmaf(h, v1B, s1);
        s2 = fmaf(h, v2B, s2);
        swf += h;
        sdf = fmaf(h, dB, sdf);
        TB[i+1] = TB[i] * (1.0f - opB);
    }
    float incB = TB[8];
    #pragma unroll
    for (int d = 1; d < 8; d <<= 1) { float o = __shfl_up(incB, d, 64); if (t >= d) incB *= o; }
    float exB; { float s = __shfl_up(incB, 1, 64); exB = (t == 0) ? 1.0f : s; }
    #pragma unroll
    for (int i = 0; i < 8; i++) cpb[8*t + i][rl] = exB * TB[i+1];    // PB inclusive
    s0 *= exB; s1 *= exB; s2 *= exB; swf *= exB; sdf *= exB;
    __syncthreads();

    // ================= phase 3b: coarse-side (own 8 coarse points) =================
    const float f63 = fde[63][rl];
    #pragma unroll
    for (int i = 0; i < 8; i++) {
        float d  = fmaf((float)(8*t + i), STEPV, NEARV);
        float op = sig_pm(bA[0] + d*sA[0]);
        float v0 = sig_pm(bA[1] + d*sA[1]);
        float v1 = sig_pm(bA[2] + d*sA[2]);
        float v2 = sig_pm(bA[3] + d*sA[3]);
        int lo = 0;
        #pragma unroll
        for (int s = 32; s >= 1; s >>= 1) {              // jB = #{k: fdep_k < d} (strict)
            float f = fde[lo + s - 1][rl];
            if (f < d) lo += s;
        }
        int jB = (f63 < d) ? 64 : lo;
        float PBg = (jB == 0) ? 1.0f : cpb[min(jB - 1, 63)][rl];
        float w2 = op * (exA * Tloc[i]) * PBg;
        s0 = fmaf(w2, v0, s0);
        s1 = fmaf(w2, v1, s1);
        s2 = fmaf(w2, v2, s2);
        swf += w2;
        sdf = fmaf(w2, d, sdf);
    }
    #pragma unroll
    for (int m = 1; m < 8; m <<= 1) {
        s0  += __shfl_xor(s0,  m, 64);
        s1  += __shfl_xor(s1,  m, 64);
        s2  += __shfl_xor(s2,  m, 64);
        swf += __shfl_xor(swf, m, 64);
        sdf += __shfl_xor(sdf, m, 64);
    }
    float fop  = fminf(fmaxf(swf, 0.0f), 1.0f);
    float rdep = sdf + (1.0f - fop) * 2.0f;              // d_all.max() == 2.0 exactly
    if (t == 0) {
        out[393216 + (b*3+0)*65536 + n] = s0;
        out[393216 + (b*3+1)*65536 + n] = s1;
        out[393216 + (b*3+2)*65536 + n] = s2;
        out[786432 + r] = rdep;
    }

    // min/max via u32 atomicMin on (bits, ~bits); rdep > 0 so u32 order == float order
    unsigned ub  = __float_as_uint(rdep);
    unsigned kmn = (t == 0) ? ub  : 0xFFFFFFFFu;
    unsigned kmx = (t == 0) ? ~ub : 0xFFFFFFFFu;
    #pragma unroll
    for (int m = 32; m >= 1; m >>= 1) {
        unsigned omn = (unsigned)__shfl_xor((int)kmn, m, 64);
        unsigned omx = (unsigned)__shfl_xor((int)kmx, m, 64);
        kmn = (omn < kmn) ? omn : kmn;
        kmx = (omx < kmx) ? omx : kmx;
    }
    if ((tid & 63) == 0) {
        atomicMin(&mmx[0], kmn);
        atomicMin(&mmx[1], kmx);
    }
}

__global__ __launch_bounds__(256) void nerf_norm(float* __restrict__ out,
                                                 const unsigned int* __restrict__ mmx)
{
    int idx = blockIdx.x * 256 + threadIdx.x;
    float mn = __uint_as_float(mmx[0]);
    float mx = __uint_as_float(~mmx[1]);
    float v = out[786432 + idx];
    out[786432 + idx] = (v - mn) * __builtin_amdgcn_rcpf(mx - mn);
}

extern "C" void kernel_launch(void* const* d_in, const int* in_sizes, int n_in,
                              void* d_out, int out_size, void* d_ws, size_t ws_size,
                              hipStream_t stream) {
    (void)in_sizes; (void)n_in; (void)out_size; (void)ws_size;
    const float* tm = (const float*)d_in[0];
    const float* wq = (const float*)d_in[1];
    float* out = (float*)d_out;
    unsigned int* mmx = (unsigned int*)d_ws;
    hipMemsetAsync(d_ws, 0xFF, 8, stream);               // both min-keys -> UINT_MAX
    nerf_main<<<NRAYS/RPB, 256, 0, stream>>>(tm, wq, out, mmx);
    nerf_norm<<<NRAYS/256, 256, 0, stream>>>(out, mmx);
}

// Round 6
// 277.659 us; speedup vs baseline: 1.5933x; 1.5933x over previous
//
#include <hip/hip_runtime.h>
#include <math.h>

// 4 threads per ray (t = tid&3 owns coarse points / samples / fine points [16t,16t+16)).
// R4: thread-per-ray = 2048 waves = 2/SIMD grid cap, 56% stall. R5: tpr=8 spilled
// (50 MB scratch) + LDS conflicts. This round: tpr=4, 8192 waves, 4 waves/SIMD
// (LDS-capped: 2 padded fp32 arrays = 33.3 KB/block, 4 blocks/CU).
//  - per-ray LDS columns touched only by the ray's own 4 lanes (same wave) -> NO barriers
//  - width-4 scans/reduces = 2 shuffle steps
//  - PA from cdf identity: PA[p] = 1 - (cdf_p*S - (p+1)*1e-5)  (no 3rd array)
//  - cdf array reused for PB-inclusive after all cdf reads (program-order safe in-wave)
//  - only two 16-reg arrays with disjoint live ranges; launch_bounds(256,4) -> 128 VGPR cap

#define PTS 64
#define SEG 16
#define NRAYS (2*256*256)
#define NEARV 0.1f
#define STEPV (1.9f/63.0f)
#define INVSTEP (1.0f/(1.9f/63.0f))
#define FAR63 (0.1f + 63.0f*(1.9f/63.0f))
#define NL2E (-1.4426950408889634f)
#define LSTR 65                      // LDS row stride (pad 1) -> search probes spread banks

extern "C" __device__ float __ocml_native_exp2_f32(float);

__device__ __forceinline__ float sig_pm(float arg) {   // arg is already -x*log2e
    return __builtin_amdgcn_rcpf(1.0f + __ocml_native_exp2_f32(arg));
}

__global__ __launch_bounds__(256, 4) void nerf_main(
    const float* __restrict__ tm, const float* __restrict__ wq,
    float* __restrict__ out, unsigned int* __restrict__ mmx)
{
    __shared__ float cpb[PTS * LSTR];   // cdf (P1..P3a), then PB-inclusive (P3b)
    __shared__ float fde[PTS * LSTR];   // fine depths (P2..P3b)

    const int tid = threadIdx.x;
    const int t  = tid & 3;             // segment slot within ray
    const int rb = tid >> 2;            // ray within block (0..63)
    const int r  = blockIdx.x * 64 + rb;
    const int b  = r >> 16;
    const int n  = r & 65535;
    const int ii = n >> 8;
    const int jj = n & 255;

    const float cx = (1.0f + (float)jj * (-2.0f/255.0f)) * (1.0f/4.2f);
    const float cy = (1.0f + (float)ii * (-2.0f/255.0f)) * (1.0f/4.2f);

    const float* tmb = tm + b*12;
    const float dx = tmb[0]*cx + tmb[1]*cy + tmb[2];
    const float dy = tmb[4]*cx + tmb[5]*cy + tmb[6];
    const float dz = tmb[8]*cx + tmb[9]*cy + tmb[10];
    const float ox = tmb[3], oy = tmb[7], oz = tmb[11];

    float bA[4], sA[4];                 // feat[c]*(-log2e) = bA[c] + d*sA[c]
    #pragma unroll
    for (int c = 0; c < 4; c++) {
        float s  = dx*wq[0*4+c] + dy*wq[1*4+c] + dz*wq[2*4+c];
        float bb = ox*wq[0*4+c] + oy*wq[1*4+c] + oz*wq[2*4+c]
                 + dx*wq[3*4+c] + dy*wq[4*4+c] + dz*wq[5*4+c];
        sA[c] = s * NL2E;
        bA[c] = bb * NL2E;
    }

    // ============ P1: coarse segment [16t, 16t+16) ============
    float cum[SEG];                     // local cumulative w (no eps, no exA)
    float Trun = 1.0f, sv0 = 0.0f, sv1 = 0.0f, sv2 = 0.0f, cacc = 0.0f;
    #pragma unroll
    for (int i = 0; i < SEG; i++) {
        float d  = fmaf((float)(SEG*t + i), STEPV, NEARV);
        float op = sig_pm(bA[0] + d*sA[0]);
        float v0 = sig_pm(bA[1] + d*sA[1]);
        float v1 = sig_pm(bA[2] + d*sA[2]);
        float v2 = sig_pm(bA[3] + d*sA[3]);
        float w  = op * Trun;
        cacc += w;
        cum[i] = cacc;
        sv0 = fmaf(w, v0, sv0);
        sv1 = fmaf(w, v1, sv1);
        sv2 = fmaf(w, v2, sv2);
        Trun *= (1.0f - op);
    }
    // exclusive product of segment transmittances (width-4 scan: 2 steps)
    float Ti = Trun;
    { float o = __shfl_up(Ti, 1, 64); if (t >= 1) Ti *= o;
      o = __shfl_up(Ti, 2, 64); if (t >= 2) Ti *= o; }
    float exA; { float o = __shfl_up(Ti, 1, 64); exA = (t == 0) ? 1.0f : o; }

    float segW = fmaf(exA, cum[SEG-1], (float)SEG * 1e-5f);
    float S = segW;
    S += __shfl_xor(S, 1, 64); S += __shfl_xor(S, 2, 64);
    float Wi = segW;
    { float o = __shfl_up(Wi, 1, 64); if (t >= 1) Wi += o;
      o = __shfl_up(Wi, 2, 64); if (t >= 2) Wi += o; }
    float Wexc; { float o = __shfl_up(Wi, 1, 64); Wexc = (t == 0) ? 0.0f : o; }
    const float Sinv = __builtin_amdgcn_rcpf(S);

    float a0 = exA*sv0, a1 = exA*sv1, a2 = exA*sv2;
    a0 += __shfl_xor(a0, 1, 64); a0 += __shfl_xor(a0, 2, 64);
    a1 += __shfl_xor(a1, 1, 64); a1 += __shfl_xor(a1, 2, 64);
    a2 += __shfl_xor(a2, 1, 64); a2 += __shfl_xor(a2, 2, 64);
    if (t == 0) {
        out[(b*3+0)*65536 + n] = a0;
        out[(b*3+1)*65536 + n] = a1;
        out[(b*3+2)*65536 + n] = a2;
    }
    #pragma unroll
    for (int i = 0; i < SEG; i++) {     // cdf_p = (Wexc + exA*cum_i + (i+1)*1e-5)/S
        float cdfv = (Wexc + fmaf(exA, cum[i], (float)(i+1) * 1e-5f)) * Sinv;
        cpb[(SEG*t + i)*LSTR + rb] = cdfv;
    }
    __builtin_amdgcn_wave_barrier();    // in-wave producers/consumers; no block barrier needed

    // ============ P2: bins for u=(16t+m)/64, m=0..16; fine depths ============
    const float c63 = cpb[63*LSTR + rb];
    float fdr[SEG];
    float bin_prev = 0.0f;
    #pragma unroll
    for (int m = 0; m <= SEG; m++) {
        float u = (float)(SEG*t + m) * 0.015625f;        // exact k/64
        int lo = 0;
        #pragma unroll
        for (int s = 32; s >= 1; s >>= 1) {              // searchsorted 'right', idx<=62
            float cc = cpb[(lo + s - 1)*LSTR + rb];
            if (cc <= u) lo += s;
        }
        int ind = (c63 <= u) ? 64 : lo;
        int below = min(max(ind - 1, 0), 63);
        int above = min(ind, 63);
        float c0 = cpb[below*LSTR + rb];
        float c1 = cpb[above*LSTR + rb];
        float d0 = fmaf((float)below, STEPV, NEARV);
        float d1 = fmaf((float)above, STEPV, NEARV);
        float den = c1 - c0;
        den = (den < 1e-8f) ? 1.0f : den;                // ref guard
        float tt = (u - c0) * __builtin_amdgcn_rcpf(den);
        tt = fminf(fmaxf(tt, 0.0f), 1.0f);
        float bin = fmaf(tt, d1 - d0, d0);
        if (m > 0) {
            fdr[m-1] = 0.5f * (bin_prev + bin);
            fde[(SEG*t + m - 1)*LSTR + rb] = fdr[m-1];
        }
        bin_prev = bin;
    }
    __builtin_amdgcn_wave_barrier();

    // ============ P3a: fine-side (own 16 fine points, fdr in regs) ============
    float tbl[SEG];
    float TB = 1.0f, s0 = 0.0f, s1 = 0.0f, s2 = 0.0f, swf = 0.0f, sdf = 0.0f;
    #pragma unroll
    for (int i = 0; i < SEG; i++) {
        float dB  = fdr[i];
        float opB = sig_pm(bA[0] + dB*sA[0]);
        float v0B = sig_pm(bA[1] + dB*sA[1]);
        float v1B = sig_pm(bA[2] + dB*sA[2]);
        float v2B = sig_pm(bA[3] + dB*sA[3]);
        // jA = #{p: d_p <= dB}: closed-form + exact-compare fixup (R5-validated)
        int q0 = (int)floorf((dB - NEARV) * INVSTEP);
        float g0 = fmaf((float)q0,     STEPV, NEARV);
        float g1 = fmaf((float)(q0+1), STEPV, NEARV);
        int jA = q0 + ((g0 <= dB) ? 1 : 0) + ((g1 <= dB) ? 1 : 0);
        float cv = cpb[max(jA - 1, 0)*LSTR + rb];
        float PAg = 1.0f + (float)jA * 1e-5f - cv * S;   // identity: PA = 1-(cdf*S - jA*1e-5)
        PAg = (jA == 0) ? 1.0f : PAg;
        float h = opB * TB * PAg;                        // exB applied after scan
        s0 = fmaf(h, v0B, s0);
        s1 = fmaf(h, v1B, s1);
        s2 = fmaf(h, v2B, s2);
        swf += h;
        sdf = fmaf(h, dB, sdf);
        TB *= (1.0f - opB);
        tbl[i] = TB;                                     // local inclusive products
    }
    float TBi = TB;
    { float o = __shfl_up(TBi, 1, 64); if (t >= 1) TBi *= o;
      o = __shfl_up(TBi, 2, 64); if (t >= 2) TBi *= o; }
    float exB; { float o = __shfl_up(TBi, 1, 64); exB = (t == 0) ? 1.0f : o; }
    s0 *= exB; s1 *= exB; s2 *= exB; swf *= exB; sdf *= exB;
    __builtin_amdgcn_wave_barrier();                     // all cdf reads done
    #pragma unroll
    for (int i = 0; i < SEG; i++)                        // overwrite cdf with PB-inclusive
        cpb[(SEG*t + i)*LSTR + rb] = exB * tbl[i];
    __builtin_amdgcn_wave_barrier();

    // ============ P3b: coarse-side (own 16 coarse points) ============
    const float f63 = fde[63*LSTR + rb];
    float TA = exA;                                      // global exclusive seed
    #pragma unroll
    for (int i = 0; i < SEG; i++) {
        float d  = fmaf((float)(SEG*t + i), STEPV, NEARV);
        float op = sig_pm(bA[0] + d*sA[0]);
        float v0 = sig_pm(bA[1] + d*sA[1]);
        float v1 = sig_pm(bA[2] + d*sA[2]);
        float v2 = sig_pm(bA[3] + d*sA[3]);
        int lo = 0;
        #pragma unroll
        for (int s = 32; s >= 1; s >>= 1) {              // jB = #{k: fdep_k < d} (strict)
            float ff = fde[(lo + s - 1)*LSTR + rb];
            if (ff < d) lo += s;
        }
        int jB = (f63 < d) ? 64 : lo;
        float pbv = cpb[max(jB - 1, 0)*LSTR + rb];
        float PBg = (jB == 0) ? 1.0f : pbv;
        float w2 = op * TA * PBg;
        s0 = fmaf(w2, v0, s0);
        s1 = fmaf(w2, v1, s1);
        s2 = fmaf(w2, v2, s2);
        swf += w2;
        sdf = fmaf(w2, d, sdf);
        TA *= (1.0f - op);
    }
    s0  += __shfl_xor(s0, 1, 64);  s0  += __shfl_xor(s0, 2, 64);
    s1  += __shfl_xor(s1, 1, 64);  s1  += __shfl_xor(s1, 2, 64);
    s2  += __shfl_xor(s2, 1, 64);  s2  += __shfl_xor(s2, 2, 64);
    swf += __shfl_xor(swf, 1, 64); swf += __shfl_xor(swf, 2, 64);
    sdf += __shfl_xor(sdf, 1, 64); sdf += __shfl_xor(sdf, 2, 64);

    float fop  = fminf(fmaxf(swf, 0.0f), 1.0f);
    float rdep = sdf + (1.0f - fop) * 2.0f;              // d_all.max() == 2.0 exactly
    if (t == 0) {
        out[393216 + (b*3+0)*65536 + n] = s0;
        out[393216 + (b*3+1)*65536 + n] = s1;
        out[393216 + (b*3+2)*65536 + n] = s2;
        out[786432 + r] = rdep;
    }

    // block min/max: all lanes hold their ray's rdep (duplicates harmless for min/max)
    unsigned ub  = __float_as_uint(rdep);
    unsigned kmn = ub, kmx = ~ub;
    #pragma unroll
    for (int m = 32; m >= 1; m >>= 1) {
        unsigned omn = (unsigned)__shfl_xor((int)kmn, m, 64);
        unsigned omx = (unsigned)__shfl_xor((int)kmx, m, 64);
        kmn = (omn < kmn) ? omn : kmn;
        kmx = (omx < kmx) ? omx : kmx;
    }
    if ((tid & 63) == 0) {
        atomicMin(&mmx[0], kmn);
        atomicMin(&mmx[1], kmx);
    }
}

__global__ __launch_bounds__(256) void nerf_norm(float* __restrict__ out,
                                                 const unsigned int* __restrict__ mmx)
{
    int idx = blockIdx.x * 256 + threadIdx.x;
    float mn = __uint_as_float(mmx[0]);
    float mx = __uint_as_float(~mmx[1]);
    float v = out[786432 + idx];
    out[786432 + idx] = (v - mn) * __builtin_amdgcn_rcpf(mx - mn);
}

extern "C" void kernel_launch(void* const* d_in, const int* in_sizes, int n_in,
                              void* d_out, int out_size, void* d_ws, size_t ws_size,
                              hipStream_t stream) {
    (void)in_sizes; (void)n_in; (void)out_size; (void)ws_size;
    const float* tm = (const float*)d_in[0];
    const float* wq = (const float*)d_in[1];
    float* out = (float*)d_out;
    unsigned int* mmx = (unsigned int*)d_ws;
    hipMemsetAsync(d_ws, 0xFF, 8, stream);               // both min-keys -> UINT_MAX
    nerf_main<<<NRAYS/64, 256, 0, stream>>>(tm, wq, out, mmx);
    nerf_norm<<<NRAYS/256, 256, 0, stream>>>(out, mmx);
}

// Round 7
// 169.120 us; speedup vs baseline: 2.6158x; 1.6418x over previous
//
#include <hip/hip_runtime.h>
#include <math.h>

// Thread-per-ray (R4 structure, 85 us proven; R5/R6 multi-thread-per-ray spilled).
// Hard cap: 2048 waves = 2/SIMD (grid = ray count). This round:
//  (a) P3 merge unrolled x2: pair's 8 transcendentals are independent -> ILP over
//      the dependency stalls 2 waves/SIMD can't hide; 3-deep LDS window w0..w2.
//  (b) single-kernel min/max+normalize: 1024 blocks @ 33,280 B LDS = exactly 4
//      blocks/CU co-resident -> counter-spin grid barrier is deadlock-free.
//      Per-block partials -> release fetch_add -> acquire spin -> every block
//      reduces the 1024 partial pairs (L2-hit) and normalizes its own 128 rdeps
//      still in registers. Kills norm kernel + raw-depth traffic + 1 memset node.

#define NT 128
#define PTS 64
#define NRAYS (2*256*256)
#define NBLK (NRAYS/NT)          // 1024
#define NEARV 0.1f
#define STEPV (1.9f/63.0f)
#define FAR63 (0.1f + 63.0f*(1.9f/63.0f))
#define NL2E (-1.4426950408889634f)

extern "C" __device__ float __ocml_native_exp2_f32(float);

__device__ __forceinline__ float sig_pm(float arg) {   // arg is already -x*log2e
    return __builtin_amdgcn_rcpf(1.0f + __ocml_native_exp2_f32(arg));
}

__global__ __launch_bounds__(NT) void nerf_main(
    const float* __restrict__ tm, const float* __restrict__ wq,
    float* __restrict__ out, unsigned int* __restrict__ cnt,
    float* __restrict__ part)
{
    __shared__ float fd[PTS + 1][NT];      // 64 fine depths + junk pad row = 33280 B
    __shared__ float smm[4];               // cross-wave {min0,min1,max0,max1}
    const int tid = threadIdx.x;
    const int r = blockIdx.x * NT + tid;
    const int b = r >> 16;
    const int n = r & 65535;
    const int i = n >> 8;
    const int j = n & 255;

    const float cx = (1.0f + (float)j * (-2.0f/255.0f)) * (1.0f/4.2f);
    const float cy = (1.0f + (float)i * (-2.0f/255.0f)) * (1.0f/4.2f);

    const float* tmb = tm + b*12;
    const float dx = tmb[0]*cx + tmb[1]*cy + tmb[2];
    const float dy = tmb[4]*cx + tmb[5]*cy + tmb[6];
    const float dz = tmb[8]*cx + tmb[9]*cy + tmb[10];
    const float ox = tmb[3], oy = tmb[7], oz = tmb[11];

    float bA[4], sA[4];                    // feat[c]*(-log2e) = bA[c] + d*sA[c]
    #pragma unroll
    for (int c = 0; c < 4; c++) {
        float s  = dx*wq[0*4+c] + dy*wq[1*4+c] + dz*wq[2*4+c];
        float bb = ox*wq[0*4+c] + oy*wq[1*4+c] + oz*wq[2*4+c]
                 + dx*wq[3*4+c] + dy*wq[4*4+c] + dz*wq[5*4+c];
        sA[c] = s * NL2E;
        bA[c] = bb * NL2E;
    }

    // ---- phase 1: coarse march (unchanged from R4) ----
    float T = 1.0f, S = 0.0f, a0 = 0.0f, a1 = 0.0f, a2 = 0.0f;
    #pragma unroll 8
    for (int p = 0; p < PTS; p++) {
        float d  = fmaf((float)p, STEPV, NEARV);
        float op = sig_pm(bA[0] + d*sA[0]);
        float v0 = sig_pm(bA[1] + d*sA[1]);
        float v1 = sig_pm(bA[2] + d*sA[2]);
        float v2 = sig_pm(bA[3] + d*sA[3]);
        float w  = op * T;
        a0 = fmaf(w, v0, a0); a1 = fmaf(w, v1, a1); a2 = fmaf(w, v2, a2);
        S  += w + 1e-5f;
        T  *= (1.0f - op);
    }
    out[(b*3+0)*65536 + n] = a0;
    out[(b*3+1)*65536 + n] = a1;
    out[(b*3+2)*65536 + n] = a2;

    // ---- phase 2: branchless sampling machine (unchanged from R4) ----
    const float Sinv = __builtin_amdgcn_rcpf(S);
    float op0 = sig_pm(bA[0] + NEARV*sA[0]);
    float T2   = 1.0f - op0;
    float c_lo = 0.0f;
    float c_hi = (op0 + 1e-5f) * Sinv;     // cdf[0]
    int ind = 0, k = 1;
    float bin_prev = NEARV;                // bin_0 == NEAR always (u=0 < cdf[0])
    #pragma unroll 1
    for (int it = 0; it < 2*PTS; it++) {
        float u = (float)k * 0.015625f;    // exact k/64
        bool adv = (ind < PTS) && (c_hi <= u);     // searchsorted 'right'
        float dn  = fmaf((float)min(ind + 1, 63), STEPV, NEARV);
        float opn = sig_pm(bA[0] + dn*sA[0]);
        float wn  = opn * T2;
        float d0  = fmaf((float)(ind - 1), STEPV, NEARV);
        float den = c_hi - c_lo;
        den = (den < 1e-8f) ? 1.0f : den;  // ref guard
        float t = (u - c_lo) * __builtin_amdgcn_rcpf(den);
        t = fminf(fmaxf(t, 0.0f), 1.0f);
        float bin = fmaf(t, STEPV, d0);
        bin = (ind <= 0)   ? NEARV : bin;
        bin = (ind >= PTS) ? FAR63 : bin;
        float fdep = 0.5f * (bin_prev + bin);
        if (adv) {
            ind++; c_lo = c_hi; c_hi = c_hi + (wn + 1e-5f) * Sinv; T2 *= (1.0f - opn);
        } else {
            fd[min(k - 1, PTS)][tid] = fdep;   // k>64 lands in pad row
            bin_prev = bin; k++;
        }
    }

    // ---- phase 3: merge, unrolled x2 (pair's 8 trans independent -> ILP) ----
    float T3 = 1.0f, sw = 0.0f, f0 = 0.0f, f1 = 0.0f, f2 = 0.0f, rd = 0.0f;
    int pc = 0, pf = 0;
    float dc = NEARV;
    float w0 = fd[0][tid], w1 = fd[1][tid], w2 = fd[2][tid];
    #pragma unroll 1
    for (int it = 0; it < PTS; it++) {     // 64 pairs = 128 positions
        // position 1 decision
        float dfv1 = (pf < PTS) ? w0 : 3.0e38f;
        bool tc1 = (pc < PTS) && (dc <= dfv1);     // ties -> coarse (stable argsort)
        float d_1 = tc1 ? dc : dfv1;
        int pc1 = pc + (tc1 ? 1 : 0);
        int pfn1 = pf + (tc1 ? 0 : 1);
        float dc1 = fmaf((float)pc1, STEPV, NEARV);
        // position 2 decision (window value without reload)
        float wv = tc1 ? w0 : w1;
        float dfv2 = (pfn1 < PTS) ? wv : 3.0e38f;
        bool tc2 = (pc1 < PTS) && (dc1 <= dfv2);
        float d_2 = tc2 ? dc1 : dfv2;
        int pc2 = pc1 + (tc2 ? 1 : 0);
        int pf2 = pfn1 + (tc2 ? 0 : 1);
        float dc2 = fmaf((float)pc2, STEPV, NEARV);
        // refill 3-deep window early (2 unconditional ds_reads; pad row if exhausted)
        int kc = pf2 - pf;                 // fine consumed this pair: 0,1,2
        float nw0 = (kc == 0) ? w0 : ((kc == 1) ? w1 : w2);
        float nw1 = fd[min(pf2 + 1, PTS)][tid];
        float nw2 = fd[min(pf2 + 2, PTS)][tid];
        // 8 independent transcendental chains
        float op1 = sig_pm(bA[0] + d_1*sA[0]);
        float v01 = sig_pm(bA[1] + d_1*sA[1]);
        float v11 = sig_pm(bA[2] + d_1*sA[2]);
        float v21 = sig_pm(bA[3] + d_1*sA[3]);
        float op2 = sig_pm(bA[0] + d_2*sA[0]);
        float v02 = sig_pm(bA[1] + d_2*sA[1]);
        float v12 = sig_pm(bA[2] + d_2*sA[2]);
        float v22 = sig_pm(bA[3] + d_2*sA[3]);
        float wA = op1 * T3;
        float Tm = T3 * (1.0f - op1);
        float wB = op2 * Tm;
        T3 = Tm * (1.0f - op2);
        f0 = fmaf(wA, v01, fmaf(wB, v02, f0));
        f1 = fmaf(wA, v11, fmaf(wB, v12, f1));
        f2 = fmaf(wA, v21, fmaf(wB, v22, f2));
        sw += wA + wB;
        rd = fmaf(wA, d_1, fmaf(wB, d_2, rd));
        pc = pc2; dc = dc2; pf = pf2;
        w0 = nw0; w1 = nw1; w2 = nw2;
    }
    out[393216 + (b*3+0)*65536 + n] = f0;
    out[393216 + (b*3+1)*65536 + n] = f1;
    out[393216 + (b*3+2)*65536 + n] = f2;

    float fop  = fminf(fmaxf(sw, 0.0f), 1.0f);
    float rdep = rd + (1.0f - fop) * 2.0f;         // d_all.max() == 2.0 exactly

    // ---- fused min/max + normalize (grid barrier; 4 blocks/CU co-resident) ----
    float mn = rdep, mx = rdep;
    #pragma unroll
    for (int m = 32; m >= 1; m >>= 1) {
        mn = fminf(mn, __shfl_xor(mn, m, 64));
        mx = fmaxf(mx, __shfl_xor(mx, m, 64));
    }
    if ((tid & 63) == 0) { smm[tid >> 6] = mn; smm[2 + (tid >> 6)] = mx; }
    __syncthreads();
    if (tid == 0) {
        part[2*blockIdx.x]     = fminf(smm[0], smm[1]);
        part[2*blockIdx.x + 1] = fmaxf(smm[2], smm[3]);
        __hip_atomic_fetch_add(cnt, 1u, __ATOMIC_RELEASE, __HIP_MEMORY_SCOPE_AGENT);
        while (__hip_atomic_load(cnt, __ATOMIC_ACQUIRE, __HIP_MEMORY_SCOPE_AGENT) < NBLK)
            __builtin_amdgcn_s_sleep(32);
    }
    __syncthreads();                                // all threads see counter done
    mn = 3.4e38f; mx = -3.4e38f;
    #pragma unroll 1
    for (int q = tid; q < NBLK; q += NT) {          // 8 pairs per thread, L2-hit
        float pmn = __hip_atomic_load(&part[2*q],     __ATOMIC_RELAXED, __HIP_MEMORY_SCOPE_AGENT);
        float pmx = __hip_atomic_load(&part[2*q + 1], __ATOMIC_RELAXED, __HIP_MEMORY_SCOPE_AGENT);
        mn = fminf(mn, pmn);
        mx = fmaxf(mx, pmx);
    }
    #pragma unroll
    for (int m = 32; m >= 1; m >>= 1) {
        mn = fminf(mn, __shfl_xor(mn, m, 64));
        mx = fmaxf(mx, __shfl_xor(mx, m, 64));
    }
    __syncthreads();                                // smm reuse safe
    if ((tid & 63) == 0) { smm[tid >> 6] = mn; smm[2 + (tid >> 6)] = mx; }
    __syncthreads();
    mn = fminf(smm[0], smm[1]);
    mx = fmaxf(smm[2], smm[3]);
    out[786432 + r] = (rdep - mn) * __builtin_amdgcn_rcpf(mx - mn);
}

extern "C" void kernel_launch(void* const* d_in, const int* in_sizes, int n_in,
                              void* d_out, int out_size, void* d_ws, size_t ws_size,
                              hipStream_t stream) {
    (void)in_sizes; (void)n_in; (void)out_size; (void)ws_size;
    const float* tm = (const float*)d_in[0];
    const float* wq = (const float*)d_in[1];
    float* out = (float*)d_out;
    unsigned int* cnt = (unsigned int*)d_ws;
    float* part = (float*)((char*)d_ws + 128);      // keep off the counter's line
    hipMemsetAsync(d_ws, 0, 4, stream);             // zero the arrival counter
    nerf_main<<<NBLK, NT, 0, stream>>>(tm, wq, out, cnt, part);
}

// Round 8
// 137.219 us; speedup vs baseline: 3.2239x; 1.2325x over previous
//
#include <hip/hip_runtime.h>
#include <math.h>

// TWO RAYS PER THREAD, thread-per-ray semantics otherwise (R4 numerics exactly).
// R7 forensics: busy cycles are invariant (~37.5 us); only stall-hiding matters.
// Grid caps waves at rays/64; tpr>=4 spills (R5/R6). So: halve waves, double ILP —
// each dependency stall in ray q=0's serial chains is filled by ray q=1's
// independent instructions. q-loops are fully unrolled (constant indices -> regs).
// Phase 2/3 fully branchless: conditional LDS store -> unconditional store to pad
// row; window refill -> unconditional ds_read. fd columns are per-thread only ->
// zero barriers. LDS 33.3 KB/block, 1024 blocks = 4 blocks/CU = 1 wave/SIMD.

#define NT 64
#define PTS 64
#define NRAYS (2*256*256)
#define NEARV 0.1f
#define STEPV (1.9f/63.0f)
#define FAR63 (0.1f + 63.0f*(1.9f/63.0f))
#define NL2E (-1.4426950408889634f)

extern "C" __device__ float __ocml_native_exp2_f32(float);

__device__ __forceinline__ float sig_pm(float arg) {   // arg is already -x*log2e
    return __builtin_amdgcn_rcpf(1.0f + __ocml_native_exp2_f32(arg));
}

__global__ __launch_bounds__(NT) void nerf_main(
    const float* __restrict__ tm, const float* __restrict__ wq,
    float* __restrict__ out, unsigned int* __restrict__ mmx)
{
    __shared__ float fd[2][PTS + 1][NT];   // per-ray fine depths + junk pad row
    const int tid = threadIdx.x;
    int rr[2];
    rr[0] = blockIdx.x * 128 + tid;
    rr[1] = rr[0] + 64;

    float bA[2][4], sA[2][4];              // feat[c]*(-log2e) = bA + d*sA
    int bb_[2], nn_[2];
    #pragma unroll
    for (int q = 0; q < 2; q++) {
        int r = rr[q];
        int b = r >> 16, n = r & 65535;
        bb_[q] = b; nn_[q] = n;
        int i = n >> 8, j = n & 255;
        float cx = (1.0f + (float)j * (-2.0f/255.0f)) * (1.0f/4.2f);
        float cy = (1.0f + (float)i * (-2.0f/255.0f)) * (1.0f/4.2f);
        const float* tmb = tm + b*12;
        float dx = tmb[0]*cx + tmb[1]*cy + tmb[2];
        float dy = tmb[4]*cx + tmb[5]*cy + tmb[6];
        float dz = tmb[8]*cx + tmb[9]*cy + tmb[10];
        float ox = tmb[3], oy = tmb[7], oz = tmb[11];
        #pragma unroll
        for (int c = 0; c < 4; c++) {
            float s  = dx*wq[0*4+c] + dy*wq[1*4+c] + dz*wq[2*4+c];
            float bv = ox*wq[0*4+c] + oy*wq[1*4+c] + oz*wq[2*4+c]
                     + dx*wq[3*4+c] + dy*wq[4*4+c] + dz*wq[5*4+c];
            sA[q][c] = s * NL2E;
            bA[q][c] = bv * NL2E;
        }
    }

    // ---- phase 1: coarse march, 2 rays interleaved ----
    float T[2] = {1.0f, 1.0f}, S[2] = {0.0f, 0.0f};
    float a0[2] = {0.0f, 0.0f}, a1[2] = {0.0f, 0.0f}, a2[2] = {0.0f, 0.0f};
    #pragma unroll 4
    for (int p = 0; p < PTS; p++) {
        float d = fmaf((float)p, STEPV, NEARV);
        #pragma unroll
        for (int q = 0; q < 2; q++) {
            float op = sig_pm(bA[q][0] + d*sA[q][0]);
            float v0 = sig_pm(bA[q][1] + d*sA[q][1]);
            float v1 = sig_pm(bA[q][2] + d*sA[q][2]);
            float v2 = sig_pm(bA[q][3] + d*sA[q][3]);
            float w  = op * T[q];
            a0[q] = fmaf(w, v0, a0[q]);
            a1[q] = fmaf(w, v1, a1[q]);
            a2[q] = fmaf(w, v2, a2[q]);
            S[q] += w + 1e-5f;
            T[q] *= (1.0f - op);
        }
    }
    #pragma unroll
    for (int q = 0; q < 2; q++) {
        out[(bb_[q]*3+0)*65536 + nn_[q]] = a0[q];
        out[(bb_[q]*3+1)*65536 + nn_[q]] = a1[q];
        out[(bb_[q]*3+2)*65536 + nn_[q]] = a2[q];
    }

    // ---- phase 2: branchless sampling machines, interleaved ----
    float Sinv[2], T2[2], c_lo[2], c_hi[2], bin_prev[2];
    int ind[2], kk[2];
    #pragma unroll
    for (int q = 0; q < 2; q++) {
        Sinv[q] = __builtin_amdgcn_rcpf(S[q]);
        float op0 = sig_pm(bA[q][0] + NEARV*sA[q][0]);
        T2[q]   = 1.0f - op0;
        c_lo[q] = 0.0f;
        c_hi[q] = (op0 + 1e-5f) * Sinv[q];   // cdf[0]
        ind[q] = 0; kk[q] = 1;
        bin_prev[q] = NEARV;                 // bin_0 == NEAR always
    }
    #pragma unroll 1
    for (int it = 0; it < 2*PTS; it++) {
        #pragma unroll
        for (int q = 0; q < 2; q++) {
            float u = (float)kk[q] * 0.015625f;          // exact k/64
            bool adv = (ind[q] < PTS) && (c_hi[q] <= u); // searchsorted 'right'
            float dn  = fmaf((float)min(ind[q] + 1, 63), STEPV, NEARV);
            float opn = sig_pm(bA[q][0] + dn*sA[q][0]);
            float wn  = opn * T2[q];
            float d0  = fmaf((float)(ind[q] - 1), STEPV, NEARV);
            float den = c_hi[q] - c_lo[q];
            den = (den < 1e-8f) ? 1.0f : den;            // ref guard
            float t = (u - c_lo[q]) * __builtin_amdgcn_rcpf(den);
            t = fminf(fmaxf(t, 0.0f), 1.0f);
            float bin = fmaf(t, STEPV, d0);
            bin = (ind[q] <= 0)   ? NEARV : bin;
            bin = (ind[q] >= PTS) ? FAR63 : bin;
            float fdep = 0.5f * (bin_prev[q] + bin);
            int widx = adv ? PTS : min(kk[q] - 1, PTS);  // pad row on advance
            fd[q][widx][tid] = fdep;                     // unconditional ds_write
            float nc_hi = c_hi[q] + (wn + 1e-5f) * Sinv[q];
            float nT2   = T2[q] * (1.0f - opn);
            c_lo[q]     = adv ? c_hi[q] : c_lo[q];
            c_hi[q]     = adv ? nc_hi   : c_hi[q];
            T2[q]       = adv ? nT2     : T2[q];
            bin_prev[q] = adv ? bin_prev[q] : bin;
            ind[q] += adv ? 1 : 0;
            kk[q]  += adv ? 0 : 1;
        }
    }

    // ---- phase 3: branchless merge, 2 rays interleaved ----
    float T3[2] = {1.0f, 1.0f}, sw[2] = {0.0f, 0.0f};
    float f0[2] = {0.0f, 0.0f}, f1[2] = {0.0f, 0.0f}, f2[2] = {0.0f, 0.0f};
    float rd[2] = {0.0f, 0.0f};
    int pc[2] = {0, 0}, pf[2] = {0, 0};
    float dc[2] = {NEARV, NEARV};
    float cur[2], nxt[2];
    #pragma unroll
    for (int q = 0; q < 2; q++) { cur[q] = fd[q][0][tid]; nxt[q] = fd[q][1][tid]; }
    #pragma unroll 1
    for (int it = 0; it < 2*PTS; it++) {
        #pragma unroll
        for (int q = 0; q < 2; q++) {
            float dfv = (pf[q] < PTS) ? cur[q] : 3.0e38f;
            bool tc = (pc[q] < PTS) && (dc[q] <= dfv);   // ties -> coarse (stable)
            float d = tc ? dc[q] : dfv;
            pc[q] += tc ? 1 : 0;
            dc[q] = fmaf((float)pc[q], STEPV, NEARV);
            pf[q] += tc ? 0 : 1;
            cur[q] = tc ? cur[q] : nxt[q];
            nxt[q] = fd[q][min(pf[q] + 1, PTS)][tid];    // unconditional ds_read
            float op = sig_pm(bA[q][0] + d*sA[q][0]);
            float v0 = sig_pm(bA[q][1] + d*sA[q][1]);
            float v1 = sig_pm(bA[q][2] + d*sA[q][2]);
            float v2 = sig_pm(bA[q][3] + d*sA[q][3]);
            float w  = op * T3[q];
            f0[q] = fmaf(w, v0, f0[q]);
            f1[q] = fmaf(w, v1, f1[q]);
            f2[q] = fmaf(w, v2, f2[q]);
            sw[q] += w;
            rd[q] = fmaf(w, d, rd[q]);
            T3[q] *= (1.0f - op);
        }
    }

    unsigned kmn = 0xFFFFFFFFu, kmx = 0xFFFFFFFFu;
    #pragma unroll
    for (int q = 0; q < 2; q++) {
        out[393216 + (bb_[q]*3+0)*65536 + nn_[q]] = f0[q];
        out[393216 + (bb_[q]*3+1)*65536 + nn_[q]] = f1[q];
        out[393216 + (bb_[q]*3+2)*65536 + nn_[q]] = f2[q];
        float fop  = fminf(fmaxf(sw[q], 0.0f), 1.0f);
        float rdep = rd[q] + (1.0f - fop) * 2.0f;        // d_all.max() == 2.0 exactly
        out[786432 + rr[q]] = rdep;
        unsigned ub = __float_as_uint(rdep);             // rdep>0: u32 order == float order
        kmn = min(kmn, ub);
        kmx = min(kmx, ~ub);
    }
    #pragma unroll
    for (int m = 32; m >= 1; m >>= 1) {
        unsigned omn = (unsigned)__shfl_xor((int)kmn, m, 64);
        unsigned omx = (unsigned)__shfl_xor((int)kmx, m, 64);
        kmn = (omn < kmn) ? omn : kmn;
        kmx = (omx < kmx) ? omx : kmx;
    }
    if (tid == 0) {
        atomicMin(&mmx[0], kmn);
        atomicMin(&mmx[1], kmx);
    }
}

__global__ __launch_bounds__(256) void nerf_norm(float* __restrict__ out,
                                                 const unsigned int* __restrict__ mmx)
{
    int idx = blockIdx.x * 256 + threadIdx.x;
    float mn = __uint_as_float(mmx[0]);
    float mx = __uint_as_float(~mmx[1]);
    float v = out[786432 + idx];
    out[786432 + idx] = (v - mn) * __builtin_amdgcn_rcpf(mx - mn);
}

extern "C" void kernel_launch(void* const* d_in, const int* in_sizes, int n_in,
                              void* d_out, int out_size, void* d_ws, size_t ws_size,
                              hipStream_t stream) {
    (void)in_sizes; (void)n_in; (void)out_size; (void)ws_size;
    const float* tm = (const float*)d_in[0];
    const float* wq = (const float*)d_in[1];
    float* out = (float*)d_out;
    unsigned int* mmx = (unsigned int*)d_ws;
    hipMemsetAsync(d_ws, 0xFF, 8, stream);     // both min-keys -> UINT_MAX
    nerf_main<<<NRAYS/128, NT, 0, stream>>>(tm, wq, out, mmx);
    nerf_norm<<<NRAYS/256, 256, 0, stream>>>(out, mmx);
}